// Round 6
// baseline (5060.875 us; speedup 1.0000x reference)
//
#include <hip/hip_runtime.h>
#include <cstdint>
#include <cstddef>

#define BTOT   16384
#define TSTEPS 60
#define HDIM   100
#define GDIM   400
#define NB     64
#define NTHR   256

static_assert(BTOT % NB == 0, "batch tiling");

struct TFPair { uint32_t a, b; };

__host__ __device__ constexpr uint32_t rotl32c(uint32_t v, int r){
  return (v << r) | (v >> (32 - r));
}

// Threefry-2x32, 20 rounds, exactly as jax/_src/prng.py
// KAT: tf2x32(0,0,0,0) == (0x6b200159, 0x99ba4efe)
__host__ __device__ constexpr TFPair tf2x32(uint32_t k0, uint32_t k1,
                                            uint32_t x0, uint32_t x1){
  const uint32_t ks2 = k0 ^ k1 ^ 0x1BD11BDAu;
  x0 += k0; x1 += k1;
  x0 += x1; x1 = rotl32c(x1,13); x1 ^= x0;
  x0 += x1; x1 = rotl32c(x1,15); x1 ^= x0;
  x0 += x1; x1 = rotl32c(x1,26); x1 ^= x0;
  x0 += x1; x1 = rotl32c(x1, 6); x1 ^= x0;
  x0 += k1;  x1 += ks2 + 1u;
  x0 += x1; x1 = rotl32c(x1,17); x1 ^= x0;
  x0 += x1; x1 = rotl32c(x1,29); x1 ^= x0;
  x0 += x1; x1 = rotl32c(x1,16); x1 ^= x0;
  x0 += x1; x1 = rotl32c(x1,24); x1 ^= x0;
  x0 += ks2; x1 += k0 + 2u;
  x0 += x1; x1 = rotl32c(x1,13); x1 ^= x0;
  x0 += x1; x1 = rotl32c(x1,15); x1 ^= x0;
  x0 += x1; x1 = rotl32c(x1,26); x1 ^= x0;
  x0 += x1; x1 = rotl32c(x1, 6); x1 ^= x0;
  x0 += k0;  x1 += k1 + 3u;
  x0 += x1; x1 = rotl32c(x1,17); x1 ^= x0;
  x0 += x1; x1 = rotl32c(x1,29); x1 ^= x0;
  x0 += x1; x1 = rotl32c(x1,16); x1 ^= x0;
  x0 += x1; x1 = rotl32c(x1,24); x1 ^= x0;
  x0 += k1;  x1 += ks2 + 4u;
  x0 += x1; x1 = rotl32c(x1,13); x1 ^= x0;
  x0 += x1; x1 = rotl32c(x1,15); x1 ^= x0;
  x0 += x1; x1 = rotl32c(x1,26); x1 ^= x0;
  x0 += x1; x1 = rotl32c(x1, 6); x1 ^= x0;
  x0 += ks2; x1 += k0 + 5u;
  return TFPair{x0, x1};
}

// folded keys: fold_in(key(42), 0) and fold_in(key(42), 1)
constexpr TFPair KF = tf2x32(0u, 42u, 0u, 0u);
constexpr TFPair KM = tf2x32(0u, 42u, 0u, 1u);

__device__ __forceinline__ float rcp_fast(float x){ return __builtin_amdgcn_rcpf(x); }
__device__ __forceinline__ float sigmoid_f(float x){ return rcp_fast(1.f + __expf(-x)); }
__device__ __forceinline__ float tanh_f(float x){
  float e = __expf(2.f * x);
  return 1.f - 2.f * rcp_fast(e + 1.f);
}

// noise = 0.5 * sqrt(2) * erfinv(uniform(-1,1)) reproducing jax.random.normal
// under jax_threefry_partitionable=True: counts = iota_2x32 = (hi32(n), lo32(n)),
// and for bit_width<=32 the draw is bits1 ^ bits2 (XOR of both output words).
__device__ __forceinline__ float tf_noise(uint32_t k0, uint32_t k1, uint32_t n){
  TFPair r = tf2x32(k0, k1, 0u, n);
  uint32_t bits = r.a ^ r.b;
  float u = __uint_as_float((bits >> 9) | 0x3f800000u) - 1.0f;   // [0,1)
  const float LOV = -0.99999994f;                                // nextafter(-1,0)
  float v = fmaxf(LOV, fmaf(u, 2.0f, LOV));                      // (hi-lo) rounds to 2.0f
  // XLA ErfInv f32 (Giles polynomial)
  float w = -log1pf(-v * v);
  float p;
  if (w < 5.0f){
    w -= 2.5f;
    p =              2.81022636e-08f;
    p = fmaf(p, w,   3.43273939e-07f);
    p = fmaf(p, w,  -3.5233877e-06f);
    p = fmaf(p, w,  -4.39150654e-06f);
    p = fmaf(p, w,   0.00021858087f);
    p = fmaf(p, w,  -0.00125372503f);
    p = fmaf(p, w,  -0.00417768164f);
    p = fmaf(p, w,   0.246640727f);
    p = fmaf(p, w,   1.50140941f);
  } else {
    w = sqrtf(w) - 3.0f;
    p =             -0.000200214257f;
    p = fmaf(p, w,   0.000100950558f);
    p = fmaf(p, w,   0.00134934322f);
    p = fmaf(p, w,  -0.00367342844f);
    p = fmaf(p, w,   0.00573950773f);
    p = fmaf(p, w,  -0.0076224613f);
    p = fmaf(p, w,   0.00943887047f);
    p = fmaf(p, w,   1.00167406f);
    p = fmaf(p, w,   2.83297682f);
  }
  return 0.70710678f * (p * v);   // 0.5 * sqrt2 * erfinv(v)
}

__device__ __forceinline__ float idm_act(float vel, float dv, float dx,
                                         float v0, float tg, float jx,
                                         float am, float an){
  dx = fminf(fmaxf(dx, 0.5f), 1000.0f);
  float gap = jx + fmaxf(0.0f, tg*vel + vel*dv / (2.0f * sqrtf(am*an)));
  float r  = vel / v0;  float r2 = r*r;
  float gd = gap / dx;
  float a  = am * (1.0f - r2*r2 - gd*gd);
  return fminf(fmaxf(a, -3.0f), 3.0f);
}

// divergent zero: defeats scalarization so weight loads stay on the (deep) VMEM path
// instead of s_loads that would blow the 102-SGPR file.
__device__ __forceinline__ uint32_t lane0(){ return __builtin_amdgcn_mbcnt_lo(0u, 0u); }

// acc[g][jj] += h[k] * W[k][g*100 + Q*25 + jj], k = 0..99.
// Loads 16B-aligned 28-float windows; all register indices compile-time (Q static).
template<int Q>
__device__ __forceinline__ void gemm_rows(const float* __restrict__ Wmat,
                                          const float* __restrict__ hbase,
                                          int lane, float (&acc)[4][25]){
  constexpr int W0 = (Q * 25) & ~3;   // aligned window start within the 100-col gate slab
  constexpr int S  = Q * 25 - W0;     // shift inside the window (== Q)
  const uint32_t dz = lane0();
  #pragma unroll 2
  for (int k = 0; k < HDIM; ++k){
    float hk = hbase[k * NB + lane];
    const float* rowp = Wmat + (size_t)k * GDIM;
    #pragma unroll
    for (int g = 0; g < 4; ++g){
      const float4* w4 = (const float4*)(rowp + g*100 + W0) + dz;
      float w[28];
      #pragma unroll
      for (int v = 0; v < 7; ++v){
        float4 t = w4[v];
        w[4*v+0] = t.x; w[4*v+1] = t.y; w[4*v+2] = t.z; w[4*v+3] = t.w;
      }
      #pragma unroll
      for (int jj = 0; jj < 25; ++jj)
        acc[g][jj] = fmaf(hk, w[S + jj], acc[g][jj]);
    }
  }
}

template<int Q>
__device__ __forceinline__ void load_row(const float* __restrict__ rowp,
                                         float (&dst)[4][25]){
  constexpr int W0 = (Q * 25) & ~3;
  constexpr int S  = Q * 25 - W0;
  const uint32_t dz = lane0();
  #pragma unroll
  for (int g = 0; g < 4; ++g){
    const float4* w4 = (const float4*)(rowp + g*100 + W0) + dz;
    float w[28];
    #pragma unroll
    for (int v = 0; v < 7; ++v){
      float4 t = w4[v];
      w[4*v+0] = t.x; w[4*v+1] = t.y; w[4*v+2] = t.z; w[4*v+3] = t.w;
    }
    #pragma unroll
    for (int jj = 0; jj < 25; ++jj) dst[g][jj] = w[S + jj];
  }
}

template<int Q>
__device__ void run_sim(const float* __restrict__ idm_params,
                        const float* __restrict__ idm_s,
                        const float* __restrict__ sdv_acts,
                        const float* __restrict__ Wi,
                        const float* __restrict__ Wh,
                        const float* __restrict__ bl,
                        const float* __restrict__ Wa,
                        const float* __restrict__ ba,
                        float* __restrict__ out,
                        float* __restrict__ h_T,       // [HDIM][NB], holds proj on entry
                        float* __restrict__ part_lds,  // [4][NB]
                        int lane, int bg)
{
  // c0 = proj slice for this thread's (lane, j-set)
  float c_reg[25];
  #pragma unroll
  for (int jj = 0; jj < 25; ++jj) c_reg[jj] = h_T[(Q*25 + jj)*NB + lane];

  // xz = bl + proj @ Wi[0:100]  (constant over time; lives in registers)
  float xz[4][25];
  #pragma unroll
  for (int g = 0; g < 4; ++g){
    #pragma unroll
    for (int jj = 0; jj < 25; ++jj) xz[g][jj] = bl[g*100 + Q*25 + jj];
  }
  gemm_rows<Q>(Wi, h_T, lane, xz);

  // Wi row 100 (sdv column weights) and Wa slice, preloaded to registers
  float w100[4][25];
  load_row<Q>(Wi + (size_t)HDIM * GDIM, w100);
  float wa_reg[25];
  #pragma unroll
  for (int jj = 0; jj < 25; ++jj) wa_reg[jj] = Wa[Q*25 + jj];
  const float ba0 = ba[0];

  const float* pp = idm_params + (size_t)bg * 5;
  const float p_v0 = pp[0], p_tg = pp[1], p_jx = pp[2], p_am = pp[3], p_an = pp[4];
  float ego_v = 0.f, ego_x = 0.f, prev_act = 0.f;

  for (int t = 0; t < TSTEPS; ++t){
    // ---- (A) ego/IDM/noise (redundant across waves; no LDS) ----
    const float* sp = idm_s + ((size_t)bg * TSTEPS + t) * 12;
    float4 s0 = *(const float4*)(sp);
    float4 s1 = *(const float4*)(sp + 4);
    float4 s2 = *(const float4*)(sp + 8);
    if (t == 0){ ego_v = s0.x; ego_x = s0.w; }
    else {
      ego_v = ego_v + prev_act * 0.1f;                       // ref rounding (no fma)
      ego_x = ego_x + ego_v * 0.1f + 0.5f * prev_act * 0.01f;
    }
    float fex = s2.z, mex = s2.w;
    float ef_dx = (s1.x - ego_x)*fex + (1.f-fex)*s1.w;   // s4 / s7
    float em_dx = (s1.y - ego_x)*mex + (1.f-mex)*s2.y;   // s5 / s9
    float ef_dv = (ego_v - s0.y)*fex + (1.f-fex)*s1.z;   // s1 / s6
    float em_dv = (ego_v - s0.z)*mex + (1.f-mex)*s2.x;   // s2 / s8
    float efa = idm_act(ego_v, ef_dv, ef_dx, p_v0, p_tg, p_jx, p_am, p_an);
    float ema = idm_act(ego_v, em_dv, em_dx, p_v0, p_tg, p_jx, p_am, p_an);
    uint32_t n = (uint32_t)(t * BTOT + bg);
    float nf = tf_noise(KF.a, KF.b, n);
    float nm = tf_noise(KM.a, KM.b, n);
    efa = fex*efa + (1.f-fex)*nf;
    ema = mex*ema + (1.f-mex)*nm;

    // ---- (B) z = xz + sdv*Wi[100] + h @ Wh ----
    float sdv = sdv_acts[(size_t)bg * TSTEPS + t];
    float acc[4][25];
    #pragma unroll
    for (int g = 0; g < 4; ++g){
      #pragma unroll
      for (int jj = 0; jj < 25; ++jj)
        acc[g][jj] = fmaf(sdv, w100[g][jj], xz[g][jj]);
    }
    gemm_rows<Q>(Wh, h_T, lane, acc);
    __syncthreads();   // everyone done reading old h before it's overwritten

    // ---- (C) gates, cell/hidden update, attention partial ----
    float part = 0.f;
    #pragma unroll
    for (int jj = 0; jj < 25; ++jj){
      float si = sigmoid_f(acc[0][jj]);
      float sf = sigmoid_f(acc[1][jj]);
      float tg = tanh_f(acc[2][jj]);
      float so = sigmoid_f(acc[3][jj]);
      float c  = fmaf(sf, c_reg[jj], si * tg);
      c_reg[jj] = c;
      float h = so * tanh_f(c);
      h_T[(Q*25 + jj)*NB + lane] = h;
      part = fmaf(h, wa_reg[jj], part);
    }
    part_lds[Q*NB + lane] = part;
    __syncthreads();   // h and partials visible

    // ---- (D) attention + blended action ----
    float dot = part_lds[0*NB + lane] + part_lds[1*NB + lane]
              + part_lds[2*NB + lane] + part_lds[3*NB + lane] + ba0;
    float att = sigmoid_f(5.0f * dot);
    float act = (1.f - att) * efa + att * ema;
    prev_act = act;
    if constexpr (Q == 0) out[bg * TSTEPS + t] = act;
    if constexpr (Q == 1) out[BTOT * TSTEPS + bg * TSTEPS + t] = att;
    // no barrier needed here: next write to h_T/part_lds is after the next (B) barrier
  }
}

__global__ __launch_bounds__(NTHR, 1)
void idm_sim_kernel(const float* __restrict__ sampled_z,
                    const float* __restrict__ idm_params,
                    const float* __restrict__ idm_s,
                    const float* __restrict__ sdv_acts,
                    const float* __restrict__ W1,
                    const float* __restrict__ b1,
                    const float* __restrict__ Wi,
                    const float* __restrict__ Wh,
                    const float* __restrict__ bl,
                    const float* __restrict__ Wa,
                    const float* __restrict__ ba,
                    float* __restrict__ out)
{
  __shared__ float h_T[HDIM * NB];      // h (and initially proj), transposed [k][b]
  __shared__ float part_lds[4 * NB];    // attention partial sums

  const int tid  = threadIdx.x;
  const int lane = tid & 63;
  const int q    = __builtin_amdgcn_readfirstlane(tid >> 6);
  const int b0   = blockIdx.x * NB;
  const int bg   = b0 + lane;

  // proj = sampled_z @ W1 + b1  -> h_T (conflict-free writes: lanes sweep b)
  for (int idx = tid; idx < HDIM * NB; idx += NTHR){
    int hh = idx >> 6;           // wave-uniform
    int bb = idx & 63;
    const float* szp = sampled_z + (size_t)(b0 + bb) * 6;
    float v = b1[hh];
    #pragma unroll
    for (int zz = 0; zz < 6; ++zz) v = fmaf(szp[zz], W1[zz*HDIM + hh], v);
    h_T[hh*NB + bb] = v;
  }
  __syncthreads();

  switch (q){
    case 0: run_sim<0>(idm_params, idm_s, sdv_acts, Wi, Wh, bl, Wa, ba, out, h_T, part_lds, lane, bg); break;
    case 1: run_sim<1>(idm_params, idm_s, sdv_acts, Wi, Wh, bl, Wa, ba, out, h_T, part_lds, lane, bg); break;
    case 2: run_sim<2>(idm_params, idm_s, sdv_acts, Wi, Wh, bl, Wa, ba, out, h_T, part_lds, lane, bg); break;
    default: run_sim<3>(idm_params, idm_s, sdv_acts, Wi, Wh, bl, Wa, ba, out, h_T, part_lds, lane, bg); break;
  }
}

extern "C" void kernel_launch(void* const* d_in, const int* in_sizes, int n_in,
                              void* d_out, int out_size, void* d_ws, size_t ws_size,
                              hipStream_t stream) {
  (void)in_sizes; (void)n_in; (void)d_ws; (void)ws_size; (void)out_size;
  const float* sampled_z  = (const float*)d_in[0];
  const float* idm_params = (const float*)d_in[1];
  const float* idm_s      = (const float*)d_in[2];
  const float* sdv_acts   = (const float*)d_in[3];
  const float* W1         = (const float*)d_in[4];
  const float* b1         = (const float*)d_in[5];
  const float* Wi         = (const float*)d_in[6];
  const float* Wh         = (const float*)d_in[7];
  const float* bl         = (const float*)d_in[8];
  const float* Wa         = (const float*)d_in[9];
  const float* ba         = (const float*)d_in[10];
  float* out = (float*)d_out;   // f32 read-path confirmed by r5 format probe

  dim3 grid(BTOT / NB);   // 256 blocks -> 1 per CU
  dim3 block(NTHR);
  idm_sim_kernel<<<grid, block, 0, stream>>>(sampled_z, idm_params, idm_s, sdv_acts,
                                             W1, b1, Wi, Wh, bl, Wa, ba, out);
}

// Round 7
// 5002.612 us; speedup vs baseline: 1.0116x; 1.0116x over previous
//
#include <hip/hip_runtime.h>
#include <cstdint>
#include <cstddef>

#define BTOT   16384
#define TSTEPS 60
#define HDIM   100
#define GDIM   400
#define NB     64
#define NTHR   1024   // 16 waves: wave = (gate g, quarter qq); 4 waves/SIMD

static_assert(BTOT % NB == 0, "batch tiling");

struct TFPair { uint32_t a, b; };

__host__ __device__ constexpr uint32_t rotl32c(uint32_t v, int r){
  return (v << r) | (v >> (32 - r));
}

// Threefry-2x32, 20 rounds, exactly as jax/_src/prng.py
__host__ __device__ constexpr TFPair tf2x32(uint32_t k0, uint32_t k1,
                                            uint32_t x0, uint32_t x1){
  const uint32_t ks2 = k0 ^ k1 ^ 0x1BD11BDAu;
  x0 += k0; x1 += k1;
  x0 += x1; x1 = rotl32c(x1,13); x1 ^= x0;
  x0 += x1; x1 = rotl32c(x1,15); x1 ^= x0;
  x0 += x1; x1 = rotl32c(x1,26); x1 ^= x0;
  x0 += x1; x1 = rotl32c(x1, 6); x1 ^= x0;
  x0 += k1;  x1 += ks2 + 1u;
  x0 += x1; x1 = rotl32c(x1,17); x1 ^= x0;
  x0 += x1; x1 = rotl32c(x1,29); x1 ^= x0;
  x0 += x1; x1 = rotl32c(x1,16); x1 ^= x0;
  x0 += x1; x1 = rotl32c(x1,24); x1 ^= x0;
  x0 += ks2; x1 += k0 + 2u;
  x0 += x1; x1 = rotl32c(x1,13); x1 ^= x0;
  x0 += x1; x1 = rotl32c(x1,15); x1 ^= x0;
  x0 += x1; x1 = rotl32c(x1,26); x1 ^= x0;
  x0 += x1; x1 = rotl32c(x1, 6); x1 ^= x0;
  x0 += k0;  x1 += k1 + 3u;
  x0 += x1; x1 = rotl32c(x1,17); x1 ^= x0;
  x0 += x1; x1 = rotl32c(x1,29); x1 ^= x0;
  x0 += x1; x1 = rotl32c(x1,16); x1 ^= x0;
  x0 += x1; x1 = rotl32c(x1,24); x1 ^= x0;
  x0 += k1;  x1 += ks2 + 4u;
  x0 += x1; x1 = rotl32c(x1,13); x1 ^= x0;
  x0 += x1; x1 = rotl32c(x1,15); x1 ^= x0;
  x0 += x1; x1 = rotl32c(x1,26); x1 ^= x0;
  x0 += x1; x1 = rotl32c(x1, 6); x1 ^= x0;
  x0 += ks2; x1 += k0 + 5u;
  return TFPair{x0, x1};
}

// folded keys: fold_in(key(42), 0) and fold_in(key(42), 1)
constexpr TFPair KF = tf2x32(0u, 42u, 0u, 0u);
constexpr TFPair KM = tf2x32(0u, 42u, 0u, 1u);

__device__ __forceinline__ float rcp_fast(float x){ return __builtin_amdgcn_rcpf(x); }
__device__ __forceinline__ float sigmoid_f(float x){ return rcp_fast(1.f + __expf(-x)); }
__device__ __forceinline__ float tanh_f(float x){
  float e = __expf(2.f * x);
  return 1.f - 2.f * rcp_fast(e + 1.f);
}

// jax.random.normal under threefry_partitionable: bits(n) = w0^w1 of tf(key,(0,n))
__device__ __forceinline__ float tf_noise(uint32_t k0, uint32_t k1, uint32_t n){
  TFPair r = tf2x32(k0, k1, 0u, n);
  uint32_t bits = r.a ^ r.b;
  float u = __uint_as_float((bits >> 9) | 0x3f800000u) - 1.0f;   // [0,1)
  const float LOV = -0.99999994f;                                // nextafter(-1,0)
  float v = fmaxf(LOV, fmaf(u, 2.0f, LOV));
  float w = -log1pf(-v * v);
  float p;
  if (w < 5.0f){
    w -= 2.5f;
    p =              2.81022636e-08f;
    p = fmaf(p, w,   3.43273939e-07f);
    p = fmaf(p, w,  -3.5233877e-06f);
    p = fmaf(p, w,  -4.39150654e-06f);
    p = fmaf(p, w,   0.00021858087f);
    p = fmaf(p, w,  -0.00125372503f);
    p = fmaf(p, w,  -0.00417768164f);
    p = fmaf(p, w,   0.246640727f);
    p = fmaf(p, w,   1.50140941f);
  } else {
    w = sqrtf(w) - 3.0f;
    p =             -0.000200214257f;
    p = fmaf(p, w,   0.000100950558f);
    p = fmaf(p, w,   0.00134934322f);
    p = fmaf(p, w,  -0.00367342844f);
    p = fmaf(p, w,   0.00573950773f);
    p = fmaf(p, w,  -0.0076224613f);
    p = fmaf(p, w,   0.00943887047f);
    p = fmaf(p, w,   1.00167406f);
    p = fmaf(p, w,   2.83297682f);
  }
  return 0.70710678f * (p * v);
}

__device__ __forceinline__ float idm_act(float vel, float dv, float dx,
                                         float v0, float tg, float jx,
                                         float am, float an){
  dx = fminf(fmaxf(dx, 0.5f), 1000.0f);
  float gap = jx + fmaxf(0.0f, tg*vel + vel*dv / (2.0f * sqrtf(am*an)));
  float r  = vel / v0;  float r2 = r*r;
  float gd = gap / dx;
  float a  = am * (1.0f - r2*r2 - gd*gd);
  return fminf(fmaxf(a, -3.0f), 3.0f);
}

// divergent zero: keep weight loads on the VMEM path (avoid SGPR scalarization)
__device__ __forceinline__ uint32_t lane0(){ return __builtin_amdgcn_mbcnt_lo(0u, 0u); }

// acc[jj] += h[k] * W[k][g*100 + QQ*25 + jj]  (25 cols of one gate), k=0..99
template<int QQ>
__device__ __forceinline__ void gemm25(const float* __restrict__ Wmat, int g,
                                       const float* __restrict__ hbase,
                                       int lane, float (&acc)[25]){
  constexpr int W0 = (QQ * 25) & ~3;    // aligned 28-float window inside the gate slab
  constexpr int S  = QQ * 25 - W0;      // == QQ
  const uint32_t dz = lane0();
  #pragma unroll 2
  for (int k = 0; k < HDIM; ++k){
    float hk = hbase[k * NB + lane];
    const float4* w4 = (const float4*)(Wmat + (size_t)k * GDIM + g*100 + W0) + dz;
    float w[28];
    #pragma unroll
    for (int v = 0; v < 7; ++v){
      float4 t = w4[v];
      w[4*v+0] = t.x; w[4*v+1] = t.y; w[4*v+2] = t.z; w[4*v+3] = t.w;
    }
    #pragma unroll
    for (int jj = 0; jj < 25; ++jj)
      acc[jj] = fmaf(hk, w[S + jj], acc[jj]);
  }
}

template<int QQ>
__device__ void run_sim(const float* __restrict__ idm_params,
                        const float* __restrict__ idm_s,
                        const float* __restrict__ sdv_acts,
                        const float* __restrict__ Wi,
                        const float* __restrict__ Wh,
                        const float* __restrict__ bl,
                        const float* __restrict__ ba,
                        float* __restrict__ out,
                        float* __restrict__ h_T,        // [100][64]
                        float* __restrict__ z_lds,      // [400][64]
                        float* __restrict__ c_lds,      // [100][64]
                        float* __restrict__ part_lds,   // [4][64]
                        const float* __restrict__ wi100_lds, // [400]
                        const float* __restrict__ wa_lds,    // [100]
                        int g, int lane, int bg)
{
  const int col0 = g*100 + QQ*25;       // this wave's z columns

  // xz = bl + proj @ Wi  (proj currently in h_T)
  float xz[25];
  #pragma unroll
  for (int jj = 0; jj < 25; ++jj) xz[jj] = bl[col0 + jj];
  gemm25<QQ>(Wi, g, h_T, lane, xz);

  const float ba0 = ba[0];
  const float* pp = idm_params + (size_t)bg * 5;
  const float p_v0 = pp[0], p_tg = pp[1], p_jx = pp[2], p_am = pp[3], p_an = pp[4];
  float ego_v = 0.f, ego_x = 0.f, prev_act = 0.f;

  for (int t = 0; t < TSTEPS; ++t){
    // ---- (A) ego/IDM/noise (redundant across waves; per-batch regs) ----
    const float* sp = idm_s + ((size_t)bg * TSTEPS + t) * 12;
    float4 s0 = *(const float4*)(sp);
    float4 s1 = *(const float4*)(sp + 4);
    float4 s2 = *(const float4*)(sp + 8);
    if (t == 0){ ego_v = s0.x; ego_x = s0.w; }
    else {
      ego_v = ego_v + prev_act * 0.1f;
      ego_x = ego_x + ego_v * 0.1f + 0.5f * prev_act * 0.01f;
    }
    float fex = s2.z, mex = s2.w;
    float ef_dx = (s1.x - ego_x)*fex + (1.f-fex)*s1.w;
    float em_dx = (s1.y - ego_x)*mex + (1.f-mex)*s2.y;
    float ef_dv = (ego_v - s0.y)*fex + (1.f-fex)*s1.z;
    float em_dv = (ego_v - s0.z)*mex + (1.f-mex)*s2.x;
    float efa = idm_act(ego_v, ef_dv, ef_dx, p_v0, p_tg, p_jx, p_am, p_an);
    float ema = idm_act(ego_v, em_dv, em_dx, p_v0, p_tg, p_jx, p_am, p_an);
    uint32_t n = (uint32_t)(t * BTOT + bg);
    float nf = tf_noise(KF.a, KF.b, n);
    float nm = tf_noise(KM.a, KM.b, n);
    efa = fex*efa + (1.f-fex)*nf;
    ema = mex*ema + (1.f-mex)*nm;

    // ---- (B) z slice = xz + sdv*Wi[100] + h @ Wh  (25 cols, one gate) ----
    float sdv = sdv_acts[(size_t)bg * TSTEPS + t];
    float acc[25];
    #pragma unroll
    for (int jj = 0; jj < 25; ++jj)
      acc[jj] = fmaf(sdv, wi100_lds[col0 + jj], xz[jj]);
    gemm25<QQ>(Wh, g, h_T, lane, acc);
    #pragma unroll
    for (int jj = 0; jj < 25; ++jj)
      z_lds[(col0 + jj)*NB + lane] = acc[jj];
    __syncthreads();   // bar1: z complete; h_T free to overwrite

    // ---- (C) cell/hidden update: 4 waves (g==0), 25 cols each ----
    if (g == 0){
      float part = 0.f;
      #pragma unroll
      for (int jj = 0; jj < 25; ++jj){
        int col = QQ*25 + jj;
        float zi = z_lds[(      col)*NB + lane];
        float zf = z_lds[(100 + col)*NB + lane];
        float zg = z_lds[(200 + col)*NB + lane];
        float zo = z_lds[(300 + col)*NB + lane];
        float c  = fmaf(sigmoid_f(zf), c_lds[col*NB + lane], sigmoid_f(zi) * tanh_f(zg));
        c_lds[col*NB + lane] = c;
        float h = sigmoid_f(zo) * tanh_f(c);
        h_T[col*NB + lane] = h;
        part = fmaf(h, wa_lds[col], part);
      }
      part_lds[QQ*NB + lane] = part;
    }
    __syncthreads();   // bar2: h, part visible to all

    // ---- (D) attention + blended action (all waves; per-batch regs) ----
    float dot = part_lds[0*NB + lane] + part_lds[1*NB + lane]
              + part_lds[2*NB + lane] + part_lds[3*NB + lane] + ba0;
    float att = sigmoid_f(5.0f * dot);
    float act = (1.f - att) * efa + att * ema;
    prev_act = act;
    if (g == 0 && QQ == 0) out[bg * TSTEPS + t] = act;
    if (g == 0 && QQ == 1) out[BTOT * TSTEPS + bg * TSTEPS + t] = att;
  }
}

__global__ __launch_bounds__(NTHR, 1)
void idm_sim_kernel(const float* __restrict__ sampled_z,
                    const float* __restrict__ idm_params,
                    const float* __restrict__ idm_s,
                    const float* __restrict__ sdv_acts,
                    const float* __restrict__ W1,
                    const float* __restrict__ b1,
                    const float* __restrict__ Wi,
                    const float* __restrict__ Wh,
                    const float* __restrict__ bl,
                    const float* __restrict__ Wa,
                    const float* __restrict__ ba,
                    float* __restrict__ out)
{
  __shared__ float h_T[HDIM * NB];       // 25.6 KB  h (and initially proj) [k][b]
  __shared__ float z_lds[GDIM * NB];     // 102.4 KB z = gates [400][64]
  __shared__ float c_lds[HDIM * NB];     // 25.6 KB  cell state [col][b]
  __shared__ float part_lds[4 * NB];     // 1 KB     attention partials
  __shared__ float wi100_lds[GDIM];      // 1.6 KB   Wi row 100 (sdv weights)
  __shared__ float wa_lds[HDIM];         // 0.4 KB   Wa

  const int tid  = threadIdx.x;
  const int lane = tid & 63;
  const int wid  = __builtin_amdgcn_readfirstlane(tid >> 6);
  const int g    = wid >> 2;        // gate 0..3
  const int qq   = wid & 3;         // column quarter 0..3
  const int b0   = blockIdx.x * NB;
  const int bg   = b0 + lane;

  // proj = sampled_z @ W1 + b1  -> h_T and c_lds (c0 = h0 = proj)
  for (int idx = tid; idx < HDIM * NB; idx += NTHR){
    int hh = idx >> 6;
    int bb = idx & 63;
    const float* szp = sampled_z + (size_t)(b0 + bb) * 6;
    float v = b1[hh];
    #pragma unroll
    for (int zz = 0; zz < 6; ++zz) v = fmaf(szp[zz], W1[zz*HDIM + hh], v);
    h_T[idx] = v;
    c_lds[idx] = v;
  }
  for (int idx = tid; idx < GDIM; idx += NTHR) wi100_lds[idx] = Wi[(size_t)HDIM*GDIM + idx];
  for (int idx = tid; idx < HDIM; idx += NTHR) wa_lds[idx] = Wa[idx];
  __syncthreads();

  switch (qq){
    case 0:  run_sim<0>(idm_params, idm_s, sdv_acts, Wi, Wh, bl, ba, out, h_T, z_lds, c_lds, part_lds, wi100_lds, wa_lds, g, lane, bg); break;
    case 1:  run_sim<1>(idm_params, idm_s, sdv_acts, Wi, Wh, bl, ba, out, h_T, z_lds, c_lds, part_lds, wi100_lds, wa_lds, g, lane, bg); break;
    case 2:  run_sim<2>(idm_params, idm_s, sdv_acts, Wi, Wh, bl, ba, out, h_T, z_lds, c_lds, part_lds, wi100_lds, wa_lds, g, lane, bg); break;
    default: run_sim<3>(idm_params, idm_s, sdv_acts, Wi, Wh, bl, ba, out, h_T, z_lds, c_lds, part_lds, wi100_lds, wa_lds, g, lane, bg); break;
  }
}

extern "C" void kernel_launch(void* const* d_in, const int* in_sizes, int n_in,
                              void* d_out, int out_size, void* d_ws, size_t ws_size,
                              hipStream_t stream) {
  (void)in_sizes; (void)n_in; (void)d_ws; (void)ws_size; (void)out_size;
  const float* sampled_z  = (const float*)d_in[0];
  const float* idm_params = (const float*)d_in[1];
  const float* idm_s      = (const float*)d_in[2];
  const float* sdv_acts   = (const float*)d_in[3];
  const float* W1         = (const float*)d_in[4];
  const float* b1         = (const float*)d_in[5];
  const float* Wi         = (const float*)d_in[6];
  const float* Wh         = (const float*)d_in[7];
  const float* bl         = (const float*)d_in[8];
  const float* Wa         = (const float*)d_in[9];
  const float* ba         = (const float*)d_in[10];
  float* out = (float*)d_out;   // f32 read-path confirmed by r5 format probe

  dim3 grid(BTOT / NB);   // 256 blocks -> 1 per CU (16 waves = 4/SIMD each)
  dim3 block(NTHR);
  idm_sim_kernel<<<grid, block, 0, stream>>>(sampled_z, idm_params, idm_s, sdv_acts,
                                             W1, b1, Wi, Wh, bl, Wa, ba, out);
}

// Round 8
// 1824.519 us; speedup vs baseline: 2.7738x; 2.7419x over previous
//
#include <hip/hip_runtime.h>
#include <cstdint>
#include <cstddef>

#define BTOT   16384
#define TSTEPS 60
#define HDIM   100
#define GDIM   400
#define NB     64
#define NTHR   1024   // 16 waves: wave = (gate g, quarter qq); 4 waves/SIMD

static_assert(BTOT % NB == 0, "batch tiling");

struct TFPair { uint32_t a, b; };

__host__ __device__ constexpr uint32_t rotl32c(uint32_t v, int r){
  return (v << r) | (v >> (32 - r));
}

// Threefry-2x32, 20 rounds, exactly as jax/_src/prng.py
__host__ __device__ constexpr TFPair tf2x32(uint32_t k0, uint32_t k1,
                                            uint32_t x0, uint32_t x1){
  const uint32_t ks2 = k0 ^ k1 ^ 0x1BD11BDAu;
  x0 += k0; x1 += k1;
  x0 += x1; x1 = rotl32c(x1,13); x1 ^= x0;
  x0 += x1; x1 = rotl32c(x1,15); x1 ^= x0;
  x0 += x1; x1 = rotl32c(x1,26); x1 ^= x0;
  x0 += x1; x1 = rotl32c(x1, 6); x1 ^= x0;
  x0 += k1;  x1 += ks2 + 1u;
  x0 += x1; x1 = rotl32c(x1,17); x1 ^= x0;
  x0 += x1; x1 = rotl32c(x1,29); x1 ^= x0;
  x0 += x1; x1 = rotl32c(x1,16); x1 ^= x0;
  x0 += x1; x1 = rotl32c(x1,24); x1 ^= x0;
  x0 += ks2; x1 += k0 + 2u;
  x0 += x1; x1 = rotl32c(x1,13); x1 ^= x0;
  x0 += x1; x1 = rotl32c(x1,15); x1 ^= x0;
  x0 += x1; x1 = rotl32c(x1,26); x1 ^= x0;
  x0 += x1; x1 = rotl32c(x1, 6); x1 ^= x0;
  x0 += k0;  x1 += k1 + 3u;
  x0 += x1; x1 = rotl32c(x1,17); x1 ^= x0;
  x0 += x1; x1 = rotl32c(x1,29); x1 ^= x0;
  x0 += x1; x1 = rotl32c(x1,16); x1 ^= x0;
  x0 += x1; x1 = rotl32c(x1,24); x1 ^= x0;
  x0 += k1;  x1 += ks2 + 4u;
  x0 += x1; x1 = rotl32c(x1,13); x1 ^= x0;
  x0 += x1; x1 = rotl32c(x1,15); x1 ^= x0;
  x0 += x1; x1 = rotl32c(x1,26); x1 ^= x0;
  x0 += x1; x1 = rotl32c(x1, 6); x1 ^= x0;
  x0 += ks2; x1 += k0 + 5u;
  return TFPair{x0, x1};
}

// folded keys: fold_in(key(42), 0) and fold_in(key(42), 1)
constexpr TFPair KF = tf2x32(0u, 42u, 0u, 0u);
constexpr TFPair KM = tf2x32(0u, 42u, 0u, 1u);

__device__ __forceinline__ float rcp_fast(float x){ return __builtin_amdgcn_rcpf(x); }
__device__ __forceinline__ float sigmoid_f(float x){ return rcp_fast(1.f + __expf(-x)); }
__device__ __forceinline__ float tanh_f(float x){
  float e = __expf(2.f * x);
  return 1.f - 2.f * rcp_fast(e + 1.f);
}

// jax.random.normal under threefry_partitionable: bits(n) = w0^w1 of tf(key,(0,n))
__device__ __forceinline__ float tf_noise(uint32_t k0, uint32_t k1, uint32_t n){
  TFPair r = tf2x32(k0, k1, 0u, n);
  uint32_t bits = r.a ^ r.b;
  float u = __uint_as_float((bits >> 9) | 0x3f800000u) - 1.0f;   // [0,1)
  const float LOV = -0.99999994f;                                // nextafter(-1,0)
  float v = fmaxf(LOV, fmaf(u, 2.0f, LOV));
  float w = -log1pf(-v * v);
  float p;
  if (w < 5.0f){
    w -= 2.5f;
    p =              2.81022636e-08f;
    p = fmaf(p, w,   3.43273939e-07f);
    p = fmaf(p, w,  -3.5233877e-06f);
    p = fmaf(p, w,  -4.39150654e-06f);
    p = fmaf(p, w,   0.00021858087f);
    p = fmaf(p, w,  -0.00125372503f);
    p = fmaf(p, w,  -0.00417768164f);
    p = fmaf(p, w,   0.246640727f);
    p = fmaf(p, w,   1.50140941f);
  } else {
    w = sqrtf(w) - 3.0f;
    p =             -0.000200214257f;
    p = fmaf(p, w,   0.000100950558f);
    p = fmaf(p, w,   0.00134934322f);
    p = fmaf(p, w,  -0.00367342844f);
    p = fmaf(p, w,   0.00573950773f);
    p = fmaf(p, w,  -0.0076224613f);
    p = fmaf(p, w,   0.00943887047f);
    p = fmaf(p, w,   1.00167406f);
    p = fmaf(p, w,   2.83297682f);
  }
  return 0.70710678f * (p * v);
}

__device__ __forceinline__ float idm_act(float vel, float dv, float dx,
                                         float v0, float tg, float jx,
                                         float am, float an){
  dx = fminf(fmaxf(dx, 0.5f), 1000.0f);
  float gap = jx + fmaxf(0.0f, tg*vel + vel*dv / (2.0f * sqrtf(am*an)));
  float r  = vel / v0;  float r2 = r*r;
  float gd = gap / dx;
  float a  = am * (1.0f - r2*r2 - gd*gd);
  return fminf(fmaxf(a, -3.0f), 3.0f);
}

// acc[jj] += h[k] * W[k][g*100 + QQ*25 + jj]  (25 cols of one gate), k=0..99.
// Weight addresses are wave-uniform -> compiler scalarizes to s_load (SMEM/K$ pipe),
// keeping the vector-memory TA free. v_fmac_f32 reads the weight from SGPR directly.
template<int QQ>
__device__ __forceinline__ void gemm25(const float* __restrict__ Wmat, int g,
                                       const float* __restrict__ hbase,
                                       int lane, float (&acc)[25]){
  const int col0 = g*100 + QQ*25;
  #pragma unroll 2
  for (int k = 0; k < HDIM; ++k){
    float hk = hbase[k * NB + lane];
    const float* wrow = Wmat + (size_t)k * GDIM + col0;
    #pragma unroll
    for (int jj = 0; jj < 25; ++jj)
      acc[jj] = fmaf(hk, wrow[jj], acc[jj]);
  }
}

template<int QQ>
__device__ void run_sim(const float* __restrict__ idm_params,
                        const float* __restrict__ idm_s,
                        const float* __restrict__ sdv_acts,
                        const float* __restrict__ Wi,
                        const float* __restrict__ Wh,
                        const float* __restrict__ bl,
                        const float* __restrict__ ba,
                        float* __restrict__ out,
                        float* __restrict__ h_T,        // [100][64]
                        float* __restrict__ z_lds,      // [400][64]
                        float* __restrict__ c_lds,      // [100][64]
                        float* __restrict__ part_lds,   // [4][64]
                        const float* __restrict__ wi100_lds, // [400]
                        const float* __restrict__ wa_lds,    // [100]
                        int g, int lane, int bg)
{
  const int col0 = g*100 + QQ*25;       // this wave's z columns

  // xz = bl + proj @ Wi  (proj currently in h_T)
  float xz[25];
  #pragma unroll
  for (int jj = 0; jj < 25; ++jj) xz[jj] = bl[col0 + jj];
  gemm25<QQ>(Wi, g, h_T, lane, xz);

  const float ba0 = ba[0];
  const float* pp = idm_params + (size_t)bg * 5;
  const float p_v0 = pp[0], p_tg = pp[1], p_jx = pp[2], p_am = pp[3], p_an = pp[4];
  float ego_v = 0.f, ego_x = 0.f, prev_act = 0.f;

  for (int t = 0; t < TSTEPS; ++t){
    // ---- (A) ego/IDM/noise (redundant across waves; per-batch regs) ----
    const float* sp = idm_s + ((size_t)bg * TSTEPS + t) * 12;
    float4 s0 = *(const float4*)(sp);
    float4 s1 = *(const float4*)(sp + 4);
    float4 s2 = *(const float4*)(sp + 8);
    if (t == 0){ ego_v = s0.x; ego_x = s0.w; }
    else {
      ego_v = ego_v + prev_act * 0.1f;
      ego_x = ego_x + ego_v * 0.1f + 0.5f * prev_act * 0.01f;
    }
    float fex = s2.z, mex = s2.w;
    float ef_dx = (s1.x - ego_x)*fex + (1.f-fex)*s1.w;
    float em_dx = (s1.y - ego_x)*mex + (1.f-mex)*s2.y;
    float ef_dv = (ego_v - s0.y)*fex + (1.f-fex)*s1.z;
    float em_dv = (ego_v - s0.z)*mex + (1.f-mex)*s2.x;
    float efa = idm_act(ego_v, ef_dv, ef_dx, p_v0, p_tg, p_jx, p_am, p_an);
    float ema = idm_act(ego_v, em_dv, em_dx, p_v0, p_tg, p_jx, p_am, p_an);
    uint32_t n = (uint32_t)(t * BTOT + bg);
    float nf = tf_noise(KF.a, KF.b, n);
    float nm = tf_noise(KM.a, KM.b, n);
    efa = fex*efa + (1.f-fex)*nf;
    ema = mex*ema + (1.f-mex)*nm;

    // ---- (B) z slice = xz + sdv*Wi[100] + h @ Wh  (25 cols, one gate) ----
    float sdv = sdv_acts[(size_t)bg * TSTEPS + t];
    float acc[25];
    #pragma unroll
    for (int jj = 0; jj < 25; ++jj)
      acc[jj] = fmaf(sdv, wi100_lds[col0 + jj], xz[jj]);
    gemm25<QQ>(Wh, g, h_T, lane, acc);
    #pragma unroll
    for (int jj = 0; jj < 25; ++jj)
      z_lds[(col0 + jj)*NB + lane] = acc[jj];
    __syncthreads();   // bar1: z complete; h_T free to overwrite

    // ---- (C) cell/hidden update: 4 waves (g==0), 25 cols each ----
    if (g == 0){
      float part = 0.f;
      #pragma unroll
      for (int jj = 0; jj < 25; ++jj){
        int col = QQ*25 + jj;
        float zi = z_lds[(      col)*NB + lane];
        float zf = z_lds[(100 + col)*NB + lane];
        float zg = z_lds[(200 + col)*NB + lane];
        float zo = z_lds[(300 + col)*NB + lane];
        float c  = fmaf(sigmoid_f(zf), c_lds[col*NB + lane], sigmoid_f(zi) * tanh_f(zg));
        c_lds[col*NB + lane] = c;
        float h = sigmoid_f(zo) * tanh_f(c);
        h_T[col*NB + lane] = h;
        part = fmaf(h, wa_lds[col], part);
      }
      part_lds[QQ*NB + lane] = part;
    }
    __syncthreads();   // bar2: h, part visible to all

    // ---- (D) attention + blended action (all waves; per-batch regs) ----
    float dot = part_lds[0*NB + lane] + part_lds[1*NB + lane]
              + part_lds[2*NB + lane] + part_lds[3*NB + lane] + ba0;
    float att = sigmoid_f(5.0f * dot);
    float act = (1.f - att) * efa + att * ema;
    prev_act = act;
    if (g == 0 && QQ == 0) out[bg * TSTEPS + t] = act;
    if (g == 0 && QQ == 1) out[BTOT * TSTEPS + bg * TSTEPS + t] = att;
  }
}

__global__ __launch_bounds__(NTHR, 1)
void idm_sim_kernel(const float* __restrict__ sampled_z,
                    const float* __restrict__ idm_params,
                    const float* __restrict__ idm_s,
                    const float* __restrict__ sdv_acts,
                    const float* __restrict__ W1,
                    const float* __restrict__ b1,
                    const float* __restrict__ Wi,
                    const float* __restrict__ Wh,
                    const float* __restrict__ bl,
                    const float* __restrict__ Wa,
                    const float* __restrict__ ba,
                    float* __restrict__ out)
{
  __shared__ float h_T[HDIM * NB];       // 25.6 KB  h (and initially proj) [k][b]
  __shared__ float z_lds[GDIM * NB];     // 102.4 KB z = gates [400][64]
  __shared__ float c_lds[HDIM * NB];     // 25.6 KB  cell state [col][b]
  __shared__ float part_lds[4 * NB];     // 1 KB     attention partials
  __shared__ float wi100_lds[GDIM];      // 1.6 KB   Wi row 100 (sdv weights)
  __shared__ float wa_lds[HDIM];         // 0.4 KB   Wa

  const int tid  = threadIdx.x;
  const int lane = tid & 63;
  const int wid  = __builtin_amdgcn_readfirstlane(tid >> 6);
  const int g    = wid >> 2;        // gate 0..3
  const int qq   = wid & 3;         // column quarter 0..3
  const int b0   = blockIdx.x * NB;
  const int bg   = b0 + lane;

  // proj = sampled_z @ W1 + b1  -> h_T and c_lds (c0 = h0 = proj)
  for (int idx = tid; idx < HDIM * NB; idx += NTHR){
    int hh = idx >> 6;
    int bb = idx & 63;
    const float* szp = sampled_z + (size_t)(b0 + bb) * 6;
    float v = b1[hh];
    #pragma unroll
    for (int zz = 0; zz < 6; ++zz) v = fmaf(szp[zz], W1[zz*HDIM + hh], v);
    h_T[idx] = v;
    c_lds[idx] = v;
  }
  for (int idx = tid; idx < GDIM; idx += NTHR) wi100_lds[idx] = Wi[(size_t)HDIM*GDIM + idx];
  for (int idx = tid; idx < HDIM; idx += NTHR) wa_lds[idx] = Wa[idx];
  __syncthreads();

  switch (qq){
    case 0:  run_sim<0>(idm_params, idm_s, sdv_acts, Wi, Wh, bl, ba, out, h_T, z_lds, c_lds, part_lds, wi100_lds, wa_lds, g, lane, bg); break;
    case 1:  run_sim<1>(idm_params, idm_s, sdv_acts, Wi, Wh, bl, ba, out, h_T, z_lds, c_lds, part_lds, wi100_lds, wa_lds, g, lane, bg); break;
    case 2:  run_sim<2>(idm_params, idm_s, sdv_acts, Wi, Wh, bl, ba, out, h_T, z_lds, c_lds, part_lds, wi100_lds, wa_lds, g, lane, bg); break;
    default: run_sim<3>(idm_params, idm_s, sdv_acts, Wi, Wh, bl, ba, out, h_T, z_lds, c_lds, part_lds, wi100_lds, wa_lds, g, lane, bg); break;
  }
}

extern "C" void kernel_launch(void* const* d_in, const int* in_sizes, int n_in,
                              void* d_out, int out_size, void* d_ws, size_t ws_size,
                              hipStream_t stream) {
  (void)in_sizes; (void)n_in; (void)d_ws; (void)ws_size; (void)out_size;
  const float* sampled_z  = (const float*)d_in[0];
  const float* idm_params = (const float*)d_in[1];
  const float* idm_s      = (const float*)d_in[2];
  const float* sdv_acts   = (const float*)d_in[3];
  const float* W1         = (const float*)d_in[4];
  const float* b1         = (const float*)d_in[5];
  const float* Wi         = (const float*)d_in[6];
  const float* Wh         = (const float*)d_in[7];
  const float* bl         = (const float*)d_in[8];
  const float* Wa         = (const float*)d_in[9];
  const float* ba         = (const float*)d_in[10];
  float* out = (float*)d_out;   // f32 read-path confirmed by r5 format probe

  dim3 grid(BTOT / NB);   // 256 blocks -> 1 per CU (16 waves = 4/SIMD each)
  dim3 block(NTHR);
  idm_sim_kernel<<<grid, block, 0, stream>>>(sampled_z, idm_params, idm_s, sdv_acts,
                                             W1, b1, Wi, Wh, bl, Wa, ba, out);
}

// Round 9
// 1465.724 us; speedup vs baseline: 3.4528x; 1.2448x over previous
//
#include <hip/hip_runtime.h>
#include <cstdint>
#include <cstddef>

#define BTOT   16384
#define TSTEPS 60
#define HDIM   100
#define GDIM   400
#define NB     64
#define NTHR   1024   // 16 waves: wave = (gate g, quarter qq); 4 waves/SIMD

static_assert(BTOT % NB == 0, "batch tiling");

struct TFPair { uint32_t a, b; };

__host__ __device__ constexpr uint32_t rotl32c(uint32_t v, int r){
  return (v << r) | (v >> (32 - r));
}

// Threefry-2x32, 20 rounds, exactly as jax/_src/prng.py
__host__ __device__ constexpr TFPair tf2x32(uint32_t k0, uint32_t k1,
                                            uint32_t x0, uint32_t x1){
  const uint32_t ks2 = k0 ^ k1 ^ 0x1BD11BDAu;
  x0 += k0; x1 += k1;
  x0 += x1; x1 = rotl32c(x1,13); x1 ^= x0;
  x0 += x1; x1 = rotl32c(x1,15); x1 ^= x0;
  x0 += x1; x1 = rotl32c(x1,26); x1 ^= x0;
  x0 += x1; x1 = rotl32c(x1, 6); x1 ^= x0;
  x0 += k1;  x1 += ks2 + 1u;
  x0 += x1; x1 = rotl32c(x1,17); x1 ^= x0;
  x0 += x1; x1 = rotl32c(x1,29); x1 ^= x0;
  x0 += x1; x1 = rotl32c(x1,16); x1 ^= x0;
  x0 += x1; x1 = rotl32c(x1,24); x1 ^= x0;
  x0 += ks2; x1 += k0 + 2u;
  x0 += x1; x1 = rotl32c(x1,13); x1 ^= x0;
  x0 += x1; x1 = rotl32c(x1,15); x1 ^= x0;
  x0 += x1; x1 = rotl32c(x1,26); x1 ^= x0;
  x0 += x1; x1 = rotl32c(x1, 6); x1 ^= x0;
  x0 += k0;  x1 += k1 + 3u;
  x0 += x1; x1 = rotl32c(x1,17); x1 ^= x0;
  x0 += x1; x1 = rotl32c(x1,29); x1 ^= x0;
  x0 += x1; x1 = rotl32c(x1,16); x1 ^= x0;
  x0 += x1; x1 = rotl32c(x1,24); x1 ^= x0;
  x0 += k1;  x1 += ks2 + 4u;
  x0 += x1; x1 = rotl32c(x1,13); x1 ^= x0;
  x0 += x1; x1 = rotl32c(x1,15); x1 ^= x0;
  x0 += x1; x1 = rotl32c(x1,26); x1 ^= x0;
  x0 += x1; x1 = rotl32c(x1, 6); x1 ^= x0;
  x0 += ks2; x1 += k0 + 5u;
  return TFPair{x0, x1};
}

// folded keys: fold_in(key(42), 0) and fold_in(key(42), 1)
constexpr TFPair KF = tf2x32(0u, 42u, 0u, 0u);
constexpr TFPair KM = tf2x32(0u, 42u, 0u, 1u);

__device__ __forceinline__ float rcp_fast(float x){ return __builtin_amdgcn_rcpf(x); }
__device__ __forceinline__ float sigmoid_f(float x){ return rcp_fast(1.f + __expf(-x)); }
__device__ __forceinline__ float tanh_f(float x){
  float e = __expf(2.f * x);
  return 1.f - 2.f * rcp_fast(e + 1.f);
}

// jax.random.normal under threefry_partitionable: bits(n) = w0^w1 of tf(key,(0,n))
__device__ __forceinline__ float tf_noise(uint32_t k0, uint32_t k1, uint32_t n){
  TFPair r = tf2x32(k0, k1, 0u, n);
  uint32_t bits = r.a ^ r.b;
  float u = __uint_as_float((bits >> 9) | 0x3f800000u) - 1.0f;   // [0,1)
  const float LOV = -0.99999994f;                                // nextafter(-1,0)
  float v = fmaxf(LOV, fmaf(u, 2.0f, LOV));
  float w = -log1pf(-v * v);
  float p;
  if (w < 5.0f){
    w -= 2.5f;
    p =              2.81022636e-08f;
    p = fmaf(p, w,   3.43273939e-07f);
    p = fmaf(p, w,  -3.5233877e-06f);
    p = fmaf(p, w,  -4.39150654e-06f);
    p = fmaf(p, w,   0.00021858087f);
    p = fmaf(p, w,  -0.00125372503f);
    p = fmaf(p, w,  -0.00417768164f);
    p = fmaf(p, w,   0.246640727f);
    p = fmaf(p, w,   1.50140941f);
  } else {
    w = sqrtf(w) - 3.0f;
    p =             -0.000200214257f;
    p = fmaf(p, w,   0.000100950558f);
    p = fmaf(p, w,   0.00134934322f);
    p = fmaf(p, w,  -0.00367342844f);
    p = fmaf(p, w,   0.00573950773f);
    p = fmaf(p, w,  -0.0076224613f);
    p = fmaf(p, w,   0.00943887047f);
    p = fmaf(p, w,   1.00167406f);
    p = fmaf(p, w,   2.83297682f);
  }
  return 0.70710678f * (p * v);
}

__device__ __forceinline__ float idm_act(float vel, float dv, float dx,
                                         float v0, float tg, float jx,
                                         float am, float an){
  dx = fminf(fmaxf(dx, 0.5f), 1000.0f);
  float gap = jx + fmaxf(0.0f, tg*vel + vel*dv / (2.0f * sqrtf(am*an)));
  float r  = vel / v0;  float r2 = r*r;
  float gd = gap / dx;
  float a  = am * (1.0f - r2*r2 - gd*gd);
  return fminf(fmaxf(a, -3.0f), 3.0f);
}

// acc[jj] += h[k] * W[k][col0+jj], k=0..99, in 4 chunks of 25.
// h loaded to registers per chunk (burst ds_read, then pure fma+s_load chain).
// Weight rows are wave-uniform -> s_load (SMEM/K$), consumed as SGPR fma operands.
__device__ __forceinline__ void gemm25(const float* __restrict__ Wmat, int col0,
                                       const float* __restrict__ h_T,
                                       int lane, float (&acc)[25]){
  #pragma unroll 1
  for (int half = 0; half < 4; ++half){
    const float* hb = h_T + half*25*NB + lane;
    float hreg[25];
    #pragma unroll
    for (int kk = 0; kk < 25; ++kk) hreg[kk] = hb[kk*NB];
    const float* wbase = Wmat + (size_t)(half*25)*GDIM + col0;
    #pragma unroll
    for (int kk = 0; kk < 25; ++kk){
      const float* wrow = wbase + (size_t)kk*GDIM;
      float hk = hreg[kk];
      #pragma unroll
      for (int jj = 0; jj < 25; ++jj)
        acc[jj] = fmaf(hk, wrow[jj], acc[jj]);
    }
  }
}

template<int QQ>
__device__ void run_sim(const float* __restrict__ idm_params,
                        const float* __restrict__ idm_s,
                        const float* __restrict__ sdv_acts,
                        const float* __restrict__ Wi,
                        const float* __restrict__ Wh,
                        const float* __restrict__ bl,
                        const float* __restrict__ ba,
                        float* __restrict__ out,
                        float* __restrict__ h_T,        // [100][64]
                        float* __restrict__ z_lds,      // [400][64]
                        float* __restrict__ c_lds,      // [100][64]
                        float* __restrict__ part_lds,   // [4][64]
                        const float* __restrict__ wi100_lds, // [400]
                        const float* __restrict__ wa_lds,    // [100]
                        int g, int lane, int bg)
{
  const int col0 = g*100 + QQ*25;       // this wave's z columns

  // xz = bl + proj @ Wi  (proj currently in h_T)
  float xz[25];
  #pragma unroll
  for (int jj = 0; jj < 25; ++jj) xz[jj] = bl[col0 + jj];
  gemm25(Wi, col0, h_T, lane, xz);

  const float ba0 = ba[0];
  // phase-A state only lives in g==0 waves
  float p_v0 = 0.f, p_tg = 0.f, p_jx = 0.f, p_am = 0.f, p_an = 0.f;
  if (g == 0){
    const float* pp = idm_params + (size_t)bg * 5;
    p_v0 = pp[0]; p_tg = pp[1]; p_jx = pp[2]; p_am = pp[3]; p_an = pp[4];
  }
  float ego_v = 0.f, ego_x = 0.f, prev_act = 0.f;

  for (int t = 0; t < TSTEPS; ++t){
    float efa = 0.f, ema = 0.f;
    // ---- (A) ego/IDM/noise: only the 4 g==0 waves (one per SIMD) ----
    if (g == 0){
      const float* sp = idm_s + ((size_t)bg * TSTEPS + t) * 12;
      float4 s0 = *(const float4*)(sp);
      float4 s1 = *(const float4*)(sp + 4);
      float4 s2 = *(const float4*)(sp + 8);
      if (t == 0){ ego_v = s0.x; ego_x = s0.w; }
      else {
        ego_v = ego_v + prev_act * 0.1f;
        ego_x = ego_x + ego_v * 0.1f + 0.5f * prev_act * 0.01f;
      }
      float fex = s2.z, mex = s2.w;
      float ef_dx = (s1.x - ego_x)*fex + (1.f-fex)*s1.w;
      float em_dx = (s1.y - ego_x)*mex + (1.f-mex)*s2.y;
      float ef_dv = (ego_v - s0.y)*fex + (1.f-fex)*s1.z;
      float em_dv = (ego_v - s0.z)*mex + (1.f-mex)*s2.x;
      efa = idm_act(ego_v, ef_dv, ef_dx, p_v0, p_tg, p_jx, p_am, p_an);
      ema = idm_act(ego_v, em_dv, em_dx, p_v0, p_tg, p_jx, p_am, p_an);
      uint32_t n = (uint32_t)(t * BTOT + bg);
      float nf = tf_noise(KF.a, KF.b, n);
      float nm = tf_noise(KM.a, KM.b, n);
      efa = fex*efa + (1.f-fex)*nf;
      ema = mex*ema + (1.f-mex)*nm;
    }

    // ---- (B) z slice = xz + sdv*Wi[100] + h @ Wh  (25 cols, one gate) ----
    float sdv = sdv_acts[(size_t)bg * TSTEPS + t];
    float acc[25];
    #pragma unroll
    for (int jj = 0; jj < 25; ++jj)
      acc[jj] = fmaf(sdv, wi100_lds[col0 + jj], xz[jj]);
    gemm25(Wh, col0, h_T, lane, acc);
    #pragma unroll
    for (int jj = 0; jj < 25; ++jj)
      z_lds[(col0 + jj)*NB + lane] = acc[jj];
    __syncthreads();   // bar1: z complete; h_T free to overwrite

    // ---- (C) cell/hidden update: the 4 g==1 waves (one per SIMD) ----
    if (g == 1){
      float part = 0.f;
      #pragma unroll
      for (int jj = 0; jj < 25; ++jj){
        int col = QQ*25 + jj;
        float zi = z_lds[(      col)*NB + lane];
        float zf = z_lds[(100 + col)*NB + lane];
        float zg = z_lds[(200 + col)*NB + lane];
        float zo = z_lds[(300 + col)*NB + lane];
        float c  = fmaf(sigmoid_f(zf), c_lds[col*NB + lane], sigmoid_f(zi) * tanh_f(zg));
        c_lds[col*NB + lane] = c;
        float h = sigmoid_f(zo) * tanh_f(c);
        h_T[col*NB + lane] = h;
        part = fmaf(h, wa_lds[col], part);
      }
      part_lds[QQ*NB + lane] = part;
    }
    __syncthreads();   // bar2: h, part visible to all

    // ---- (D) attention + blended action: only g==0 waves need it ----
    if (g == 0){
      float dot = part_lds[0*NB + lane] + part_lds[1*NB + lane]
                + part_lds[2*NB + lane] + part_lds[3*NB + lane] + ba0;
      float att = sigmoid_f(5.0f * dot);
      float act = (1.f - att) * efa + att * ema;
      prev_act = act;
      if (QQ == 0) out[bg * TSTEPS + t] = act;
      if (QQ == 1) out[BTOT * TSTEPS + bg * TSTEPS + t] = att;
    }
  }
}

__global__ __launch_bounds__(NTHR, 1)
void idm_sim_kernel(const float* __restrict__ sampled_z,
                    const float* __restrict__ idm_params,
                    const float* __restrict__ idm_s,
                    const float* __restrict__ sdv_acts,
                    const float* __restrict__ W1,
                    const float* __restrict__ b1,
                    const float* __restrict__ Wi,
                    const float* __restrict__ Wh,
                    const float* __restrict__ bl,
                    const float* __restrict__ Wa,
                    const float* __restrict__ ba,
                    float* __restrict__ out)
{
  __shared__ float h_T[HDIM * NB];       // 25.6 KB  h (and initially proj) [k][b]
  __shared__ float z_lds[GDIM * NB];     // 102.4 KB z = gates [400][64]
  __shared__ float c_lds[HDIM * NB];     // 25.6 KB  cell state [col][b]
  __shared__ float part_lds[4 * NB];     // 1 KB     attention partials
  __shared__ float wi100_lds[GDIM];      // 1.6 KB   Wi row 100 (sdv weights)
  __shared__ float wa_lds[HDIM];         // 0.4 KB   Wa

  const int tid  = threadIdx.x;
  const int lane = tid & 63;
  const int wid  = __builtin_amdgcn_readfirstlane(tid >> 6);
  const int g    = wid >> 2;        // gate 0..3  (wave w -> SIMD w%4: one g per SIMD)
  const int qq   = wid & 3;         // column quarter 0..3
  const int b0   = blockIdx.x * NB;
  const int bg   = b0 + lane;

  // proj = sampled_z @ W1 + b1  -> h_T and c_lds (c0 = h0 = proj)
  for (int idx = tid; idx < HDIM * NB; idx += NTHR){
    int hh = idx >> 6;
    int bb = idx & 63;
    const float* szp = sampled_z + (size_t)(b0 + bb) * 6;
    float v = b1[hh];
    #pragma unroll
    for (int zz = 0; zz < 6; ++zz) v = fmaf(szp[zz], W1[zz*HDIM + hh], v);
    h_T[idx] = v;
    c_lds[idx] = v;
  }
  for (int idx = tid; idx < GDIM; idx += NTHR) wi100_lds[idx] = Wi[(size_t)HDIM*GDIM + idx];
  for (int idx = tid; idx < HDIM; idx += NTHR) wa_lds[idx] = Wa[idx];
  __syncthreads();

  switch (qq){
    case 0:  run_sim<0>(idm_params, idm_s, sdv_acts, Wi, Wh, bl, ba, out, h_T, z_lds, c_lds, part_lds, wi100_lds, wa_lds, g, lane, bg); break;
    case 1:  run_sim<1>(idm_params, idm_s, sdv_acts, Wi, Wh, bl, ba, out, h_T, z_lds, c_lds, part_lds, wi100_lds, wa_lds, g, lane, bg); break;
    case 2:  run_sim<2>(idm_params, idm_s, sdv_acts, Wi, Wh, bl, ba, out, h_T, z_lds, c_lds, part_lds, wi100_lds, wa_lds, g, lane, bg); break;
    default: run_sim<3>(idm_params, idm_s, sdv_acts, Wi, Wh, bl, ba, out, h_T, z_lds, c_lds, part_lds, wi100_lds, wa_lds, g, lane, bg); break;
  }
}

extern "C" void kernel_launch(void* const* d_in, const int* in_sizes, int n_in,
                              void* d_out, int out_size, void* d_ws, size_t ws_size,
                              hipStream_t stream) {
  (void)in_sizes; (void)n_in; (void)d_ws; (void)ws_size; (void)out_size;
  const float* sampled_z  = (const float*)d_in[0];
  const float* idm_params = (const float*)d_in[1];
  const float* idm_s      = (const float*)d_in[2];
  const float* sdv_acts   = (const float*)d_in[3];
  const float* W1         = (const float*)d_in[4];
  const float* b1         = (const float*)d_in[5];
  const float* Wi         = (const float*)d_in[6];
  const float* Wh         = (const float*)d_in[7];
  const float* bl         = (const float*)d_in[8];
  const float* Wa         = (const float*)d_in[9];
  const float* ba         = (const float*)d_in[10];
  float* out = (float*)d_out;   // f32 read-path confirmed by r5 format probe

  dim3 grid(BTOT / NB);   // 256 blocks -> 1 per CU (16 waves = 4/SIMD each)
  dim3 block(NTHR);
  idm_sim_kernel<<<grid, block, 0, stream>>>(sampled_z, idm_params, idm_s, sdv_acts,
                                             W1, b1, Wi, Wh, bl, Wa, ba, out);
}

// Round 10
// 929.966 us; speedup vs baseline: 5.4420x; 1.5761x over previous
//
#include <hip/hip_runtime.h>
#include <cstdint>
#include <cstddef>

#define BTOT   16384
#define TSTEPS 60
#define HDIM   100
#define GDIM   400
#define NB     64
#define NTHR   1024   // 16 waves

static_assert(BTOT % NB == 0, "batch tiling");

typedef __attribute__((ext_vector_type(8))) short bf16x8;
typedef __attribute__((ext_vector_type(4))) float f32x4;

struct TFPair { uint32_t a, b; };

__host__ __device__ constexpr uint32_t rotl32c(uint32_t v, int r){
  return (v << r) | (v >> (32 - r));
}

// Threefry-2x32, 20 rounds, exactly as jax/_src/prng.py
__host__ __device__ constexpr TFPair tf2x32(uint32_t k0, uint32_t k1,
                                            uint32_t x0, uint32_t x1){
  const uint32_t ks2 = k0 ^ k1 ^ 0x1BD11BDAu;
  x0 += k0; x1 += k1;
  x0 += x1; x1 = rotl32c(x1,13); x1 ^= x0;
  x0 += x1; x1 = rotl32c(x1,15); x1 ^= x0;
  x0 += x1; x1 = rotl32c(x1,26); x1 ^= x0;
  x0 += x1; x1 = rotl32c(x1, 6); x1 ^= x0;
  x0 += k1;  x1 += ks2 + 1u;
  x0 += x1; x1 = rotl32c(x1,17); x1 ^= x0;
  x0 += x1; x1 = rotl32c(x1,29); x1 ^= x0;
  x0 += x1; x1 = rotl32c(x1,16); x1 ^= x0;
  x0 += x1; x1 = rotl32c(x1,24); x1 ^= x0;
  x0 += ks2; x1 += k0 + 2u;
  x0 += x1; x1 = rotl32c(x1,13); x1 ^= x0;
  x0 += x1; x1 = rotl32c(x1,15); x1 ^= x0;
  x0 += x1; x1 = rotl32c(x1,26); x1 ^= x0;
  x0 += x1; x1 = rotl32c(x1, 6); x1 ^= x0;
  x0 += k0;  x1 += k1 + 3u;
  x0 += x1; x1 = rotl32c(x1,17); x1 ^= x0;
  x0 += x1; x1 = rotl32c(x1,29); x1 ^= x0;
  x0 += x1; x1 = rotl32c(x1,16); x1 ^= x0;
  x0 += x1; x1 = rotl32c(x1,24); x1 ^= x0;
  x0 += k1;  x1 += ks2 + 4u;
  x0 += x1; x1 = rotl32c(x1,13); x1 ^= x0;
  x0 += x1; x1 = rotl32c(x1,15); x1 ^= x0;
  x0 += x1; x1 = rotl32c(x1,26); x1 ^= x0;
  x0 += x1; x1 = rotl32c(x1, 6); x1 ^= x0;
  x0 += ks2; x1 += k0 + 5u;
  return TFPair{x0, x1};
}

constexpr TFPair KF = tf2x32(0u, 42u, 0u, 0u);   // fold_in(key(42), 0)
constexpr TFPair KM = tf2x32(0u, 42u, 0u, 1u);   // fold_in(key(42), 1)

__device__ __forceinline__ float rcp_fast(float x){ return __builtin_amdgcn_rcpf(x); }
__device__ __forceinline__ float sigmoid_f(float x){ return rcp_fast(1.f + __expf(-x)); }
__device__ __forceinline__ float tanh_f(float x){
  float e = __expf(2.f * x);
  return 1.f - 2.f * rcp_fast(e + 1.f);
}

// jax.random.normal under threefry_partitionable: bits(n) = w0^w1 of tf(key,(0,n))
__device__ __forceinline__ float tf_noise(uint32_t k0, uint32_t k1, uint32_t n){
  TFPair r = tf2x32(k0, k1, 0u, n);
  uint32_t bits = r.a ^ r.b;
  float u = __uint_as_float((bits >> 9) | 0x3f800000u) - 1.0f;   // [0,1)
  const float LOV = -0.99999994f;                                // nextafter(-1,0)
  float v = fmaxf(LOV, fmaf(u, 2.0f, LOV));
  float w = -log1pf(-v * v);
  float p;
  if (w < 5.0f){
    w -= 2.5f;
    p =              2.81022636e-08f;
    p = fmaf(p, w,   3.43273939e-07f);
    p = fmaf(p, w,  -3.5233877e-06f);
    p = fmaf(p, w,  -4.39150654e-06f);
    p = fmaf(p, w,   0.00021858087f);
    p = fmaf(p, w,  -0.00125372503f);
    p = fmaf(p, w,  -0.00417768164f);
    p = fmaf(p, w,   0.246640727f);
    p = fmaf(p, w,   1.50140941f);
  } else {
    w = sqrtf(w) - 3.0f;
    p =             -0.000200214257f;
    p = fmaf(p, w,   0.000100950558f);
    p = fmaf(p, w,   0.00134934322f);
    p = fmaf(p, w,  -0.00367342844f);
    p = fmaf(p, w,   0.00573950773f);
    p = fmaf(p, w,  -0.0076224613f);
    p = fmaf(p, w,   0.00943887047f);
    p = fmaf(p, w,   1.00167406f);
    p = fmaf(p, w,   2.83297682f);
  }
  return 0.70710678f * (p * v);
}

__device__ __forceinline__ float idm_act(float vel, float dv, float dx,
                                         float v0, float tg, float jx,
                                         float am, float an){
  dx = fminf(fmaxf(dx, 0.5f), 1000.0f);
  float gap = jx + fmaxf(0.0f, tg*vel + vel*dv / (2.0f * sqrtf(am*an)));
  float r  = vel / v0;  float r2 = r*r;
  float gd = gap / dx;
  float a  = am * (1.0f - r2*r2 - gd*gd);
  return fminf(fmaxf(a, -3.0f), 3.0f);
}

// ---- bf16 split helpers (RNE) ----
__device__ __forceinline__ unsigned short f2bf(float f){
  uint32_t x = __float_as_uint(f);
  return (unsigned short)((x + 0x7fffu + ((x >> 16) & 1u)) >> 16);
}
__device__ __forceinline__ float bf2f(unsigned short h){
  return __uint_as_float(((uint32_t)h) << 16);
}

// ws halfword layout: WhHi[0] WhLo[51200] WiHi[102400] WiLo[153600]
// packet p = (mtile*4 + kfrag)*64 + lane; 8 bf16 per packet.
// A-frag layout (16x16x32): lane l -> row m=l&15, k = kfrag*32 + (l>>4)*8 + j
#define FRG_PACKETS (25*4*64)           // 6400
#define WS_WH_HI 0
#define WS_WH_LO 51200
#define WS_WI_HI 102400
#define WS_WI_LO 153600

__global__ void build_frags_kernel(const float* __restrict__ Wi,
                                   const float* __restrict__ Wh,
                                   unsigned short* __restrict__ ws){
  int p = blockIdx.x * 256 + threadIdx.x;
  if (p >= FRG_PACKETS) return;
  int lane = p & 63;
  int kf   = (p >> 6) & 3;
  int mt   = p >> 8;
  int zc   = mt*16 + (lane & 15);
  int kb   = kf*32 + ((lane >> 4) << 3);
  #pragma unroll
  for (int j = 0; j < 8; ++j){
    int k = kb + j;
    float vh = (k < HDIM) ? Wh[(size_t)k*GDIM + zc] : 0.f;
    float vi = (k < HDIM) ? Wi[(size_t)k*GDIM + zc] : 0.f;
    unsigned short h1 = f2bf(vh); unsigned short h2 = f2bf(vh - bf2f(h1));
    unsigned short i1 = f2bf(vi); unsigned short i2 = f2bf(vi - bf2f(i1));
    ws[WS_WH_HI + p*8 + j] = h1;
    ws[WS_WH_LO + p*8 + j] = h2;
    ws[WS_WI_HI + p*8 + j] = i1;
    ws[WS_WI_LO + p*8 + j] = i2;
  }
}

// h-frag LDS flat index: (((hl*4 + bt)*4 + kf)*64 + lane)*8 + j
__device__ __forceinline__ int hfr_idx(int hl, int bt, int kf, int lane, int j){
  return (((hl*4 + bt)*4 + kf)*64 + lane)*8 + j;
}

// 3-pass split-bf16 MFMA accumulate: acc[m][b2] += WT_tile x H_tile
__device__ __forceinline__ void mfma_accum(f32x4 (&acc)[4][2],
                                           const unsigned short* __restrict__ frg,
                                           int hiOff,               // WS_WH_HI or WS_WI_HI
                                           const unsigned short* __restrict__ hfr,
                                           int nmt, int mt0, int bt0, int lane){
  #pragma unroll 1
  for (int kf = 0; kf < 4; ++kf){
    bf16x8 Bh0 = *(const bf16x8*)&hfr[hfr_idx(0, bt0+0, kf, lane, 0)];
    bf16x8 Bl0 = *(const bf16x8*)&hfr[hfr_idx(1, bt0+0, kf, lane, 0)];
    bf16x8 Bh1 = *(const bf16x8*)&hfr[hfr_idx(0, bt0+1, kf, lane, 0)];
    bf16x8 Bl1 = *(const bf16x8*)&hfr[hfr_idx(1, bt0+1, kf, lane, 0)];
    #pragma unroll
    for (int m = 0; m < 4; ++m){
      if (m < nmt){
        int pidx = ((mt0 + m)*4 + kf)*64 + lane;
        bf16x8 Ah = *(const bf16x8*)(frg + hiOff + (size_t)pidx*8);
        bf16x8 Al = *(const bf16x8*)(frg + hiOff + 51200 + (size_t)pidx*8);
        acc[m][0] = __builtin_amdgcn_mfma_f32_16x16x32_bf16(Ah, Bh0, acc[m][0], 0,0,0);
        acc[m][0] = __builtin_amdgcn_mfma_f32_16x16x32_bf16(Ah, Bl0, acc[m][0], 0,0,0);
        acc[m][0] = __builtin_amdgcn_mfma_f32_16x16x32_bf16(Al, Bh0, acc[m][0], 0,0,0);
        acc[m][1] = __builtin_amdgcn_mfma_f32_16x16x32_bf16(Ah, Bh1, acc[m][1], 0,0,0);
        acc[m][1] = __builtin_amdgcn_mfma_f32_16x16x32_bf16(Ah, Bl1, acc[m][1], 0,0,0);
        acc[m][1] = __builtin_amdgcn_mfma_f32_16x16x32_bf16(Al, Bh1, acc[m][1], 0,0,0);
      }
    }
  }
}

#define ZP 66   // z_lds row stride (padded, breaks 4-way write conflict)

__global__ __launch_bounds__(NTHR, 1)
void idm_sim_kernel(const float* __restrict__ sampled_z,
                    const float* __restrict__ idm_params,
                    const float* __restrict__ idm_s,
                    const float* __restrict__ sdv_acts,
                    const float* __restrict__ W1,
                    const float* __restrict__ b1,
                    const float* __restrict__ Wi,
                    const float* __restrict__ Wh,
                    const float* __restrict__ bl,
                    const float* __restrict__ Wa,
                    const float* __restrict__ ba,
                    const unsigned short* __restrict__ frg,
                    float* __restrict__ out)
{
  __shared__ float z_lds[GDIM * ZP];                         // 105.6 KB  z^T [400][66]
  __shared__ __align__(16) unsigned short hfr[2*4*4*64*8];   // 32 KB  h frags hi/lo
  __shared__ float part_lds[16 * NB];                        // 4 KB   att partials
  __shared__ float noise_lds[2][2][NB];                      // 1 KB   nf/nm dbuf
  __shared__ float wi100_lds[GDIM];                          // 1.6 KB
  __shared__ float wa_lds[HDIM];                             // 0.4 KB

  const int tid  = threadIdx.x;
  const int lane = tid & 63;
  const int wid  = __builtin_amdgcn_readfirstlane(tid >> 6);
  const int b0   = blockIdx.x * NB;
  const int bg   = b0 + lane;

  // ---- init: zero h-frags (k>=100 pads must be 0, not poison/NaN) ----
  for (int i = tid; i < 2*4*4*64*8; i += NTHR) hfr[i] = 0;
  // proj = sampled_z @ W1 + b1 -> z_lds rows 0..99 (h0 = c0 = proj)
  for (int idx = tid; idx < HDIM * NB; idx += NTHR){
    int hh = idx >> 6; int bb = idx & 63;
    const float* szp = sampled_z + (size_t)(b0 + bb) * 6;
    float v = b1[hh];
    #pragma unroll
    for (int zz = 0; zz < 6; ++zz) v = fmaf(szp[zz], W1[zz*HDIM + hh], v);
    z_lds[hh*ZP + bb] = v;
  }
  for (int i = tid; i < GDIM; i += NTHR) wi100_lds[i] = Wi[(size_t)HDIM*GDIM + i];
  for (int i = tid; i < HDIM; i += NTHR) wa_lds[i] = Wa[i];
  __syncthreads();

  // ---- wave roles ----
  const int bt0   = (wid >> 3) * 2;          // btile pair {0,1} or {2,3}
  const int w8    = wid & 7;
  const int nmt   = (w8 == 7) ? 4 : 3;       // 7*3 + 4 = 25 mtiles per bt-half
  const int mt0   = w8 * 3;
  const int ncols = (wid < 4) ? 7 : 6;       // phase-C cols: 4*7 + 12*6 = 100
  const int col0  = (wid < 4) ? wid*7 : 28 + (wid - 4)*6;

  // ---- phase-C init: c0 = proj; write proj bf16 frags ----
  float c_reg[7];
  #pragma unroll
  for (int i = 0; i < 7; ++i){
    if (i < ncols){
      int col = col0 + i;
      float pv = z_lds[col*ZP + lane];
      c_reg[i] = pv;
      unsigned short ph = f2bf(pv);
      unsigned short pl = f2bf(pv - bf2f(ph));
      int ladr = (lane & 15) + (((col & 31) >> 3) << 4);
      hfr[hfr_idx(0, lane >> 4, col >> 5, ladr, col & 7)] = ph;
      hfr[hfr_idx(1, lane >> 4, col >> 5, ladr, col & 7)] = pl;
    }
  }
  __syncthreads();

  // ---- xz = bl + proj @ Wi (3-pass MFMA on Wi frags) ----
  float xzs[4][2][4];
  {
    f32x4 acc[4][2];
    #pragma unroll
    for (int m = 0; m < 4; ++m){
      if (m < nmt){
        int zb = (mt0 + m)*16 + ((lane >> 4) << 2);
        f32x4 blv = *(const f32x4*)(bl + zb);
        acc[m][0] = blv; acc[m][1] = blv;
      }
    }
    mfma_accum(acc, frg, WS_WI_HI, hfr, nmt, mt0, bt0, lane);
    #pragma unroll
    for (int m = 0; m < 4; ++m) if (m < nmt)
      #pragma unroll
      for (int b2 = 0; b2 < 2; ++b2)
        #pragma unroll
        for (int r = 0; r < 4; ++r) xzs[m][b2][r] = acc[m][b2][r];
  }

  // ---- phase-A state (wave 0 only) ----
  float p_v0=0.f, p_tg=0.f, p_jx=0.f, p_am=0.f, p_an=0.f;
  if (wid == 0){
    const float* pp = idm_params + (size_t)bg * 5;
    p_v0 = pp[0]; p_tg = pp[1]; p_jx = pp[2]; p_am = pp[3]; p_an = pp[4];
  }
  float ego_v = 0.f, ego_x = 0.f, prev_act = 0.f;
  const float ba0 = ba[0];

  const int bb0 = b0 + bt0*16 + (lane & 15);   // this lane's batch in btile 0 of pair

  for (int t = 0; t < TSTEPS; ++t){
    float efa = 0.f, ema = 0.f, fex = 0.f, mex = 0.f;
    // ---- (A) ego/IDM on wave 0; noise on waves 1,2 (double-buffered) ----
    if (wid == 0){
      const float* sp = idm_s + ((size_t)bg * TSTEPS + t) * 12;
      float4 s0 = *(const float4*)(sp);
      float4 s1 = *(const float4*)(sp + 4);
      float4 s2 = *(const float4*)(sp + 8);
      if (t == 0){ ego_v = s0.x; ego_x = s0.w; }
      else {
        ego_v = ego_v + prev_act * 0.1f;
        ego_x = ego_x + ego_v * 0.1f + 0.5f * prev_act * 0.01f;
      }
      fex = s2.z; mex = s2.w;
      float ef_dx = (s1.x - ego_x)*fex + (1.f-fex)*s1.w;
      float em_dx = (s1.y - ego_x)*mex + (1.f-mex)*s2.y;
      float ef_dv = (ego_v - s0.y)*fex + (1.f-fex)*s1.z;
      float em_dv = (ego_v - s0.z)*mex + (1.f-mex)*s2.x;
      efa = idm_act(ego_v, ef_dv, ef_dx, p_v0, p_tg, p_jx, p_am, p_an);
      ema = idm_act(ego_v, em_dv, em_dx, p_v0, p_tg, p_jx, p_am, p_an);
    } else if (wid == 1){
      noise_lds[t & 1][0][lane] = tf_noise(KF.a, KF.b, (uint32_t)(t*BTOT + bg));
    } else if (wid == 2){
      noise_lds[t & 1][1][lane] = tf_noise(KM.a, KM.b, (uint32_t)(t*BTOT + bg));
    }

    // ---- (B) z^T = xz + sdv*wi100 + h @ Wh  (split-bf16 MFMA) ----
    float sdv0 = sdv_acts[(size_t)bb0 * TSTEPS + t];
    float sdv1 = sdv_acts[(size_t)(bb0 + 16) * TSTEPS + t];
    f32x4 acc[4][2];
    #pragma unroll
    for (int m = 0; m < 4; ++m){
      if (m < nmt){
        int zb = (mt0 + m)*16 + ((lane >> 4) << 2);
        #pragma unroll
        for (int r = 0; r < 4; ++r){
          float wv = wi100_lds[zb + r];
          acc[m][0][r] = fmaf(sdv0, wv, xzs[m][0][r]);
          acc[m][1][r] = fmaf(sdv1, wv, xzs[m][1][r]);
        }
      }
    }
    mfma_accum(acc, frg, WS_WH_HI, hfr, nmt, mt0, bt0, lane);
    // write z^T to LDS: zcol = mt*16 + (lane>>4)*4 + r, batch = bt*16 + (lane&15)
    #pragma unroll
    for (int m = 0; m < 4; ++m){
      if (m < nmt){
        int zb = (mt0 + m)*16 + ((lane >> 4) << 2);
        #pragma unroll
        for (int b2 = 0; b2 < 2; ++b2){
          int cadr = (bt0 + b2)*16 + (lane & 15);
          #pragma unroll
          for (int r = 0; r < 4; ++r)
            z_lds[(zb + r)*ZP + cadr] = acc[m][b2][r];
        }
      }
    }
    __syncthreads();   // bar1: z ready

    // ---- (C) gates + cell/hidden update, all 16 waves; write h frags ----
    {
      float part = 0.f;
      #pragma unroll
      for (int i = 0; i < 7; ++i){
        if (i < ncols){
          int col = col0 + i;
          float zi = z_lds[(      col)*ZP + lane];
          float zf = z_lds[(100 + col)*ZP + lane];
          float zg = z_lds[(200 + col)*ZP + lane];
          float zo = z_lds[(300 + col)*ZP + lane];
          float c  = fmaf(sigmoid_f(zf), c_reg[i], sigmoid_f(zi) * tanh_f(zg));
          c_reg[i] = c;
          float h = sigmoid_f(zo) * tanh_f(c);
          unsigned short hh_ = f2bf(h);
          unsigned short hl_ = f2bf(h - bf2f(hh_));
          int ladr = (lane & 15) + (((col & 31) >> 3) << 4);
          hfr[hfr_idx(0, lane >> 4, col >> 5, ladr, col & 7)] = hh_;
          hfr[hfr_idx(1, lane >> 4, col >> 5, ladr, col & 7)] = hl_;
          part = fmaf(h, wa_lds[col], part);
        }
      }
      part_lds[wid*NB + lane] = part;
    }
    __syncthreads();   // bar2: h frags + partials ready

    // ---- (D) attention + blended action (wave 0) ----
    if (wid == 0){
      float dot = ba0;
      #pragma unroll
      for (int w = 0; w < 16; ++w) dot += part_lds[w*NB + lane];
      float att = sigmoid_f(5.0f * dot);
      float nf = noise_lds[t & 1][0][lane];
      float nm = noise_lds[t & 1][1][lane];
      float efb = fex*efa + (1.f-fex)*nf;
      float emb = mex*ema + (1.f-mex)*nm;
      float act = (1.f - att) * efb + att * emb;
      prev_act = act;
      out[bg * TSTEPS + t] = act;
      out[BTOT * TSTEPS + bg * TSTEPS + t] = att;
    }
  }
}

extern "C" void kernel_launch(void* const* d_in, const int* in_sizes, int n_in,
                              void* d_out, int out_size, void* d_ws, size_t ws_size,
                              hipStream_t stream) {
  (void)in_sizes; (void)n_in; (void)ws_size; (void)out_size;
  const float* sampled_z  = (const float*)d_in[0];
  const float* idm_params = (const float*)d_in[1];
  const float* idm_s      = (const float*)d_in[2];
  const float* sdv_acts   = (const float*)d_in[3];
  const float* W1         = (const float*)d_in[4];
  const float* b1         = (const float*)d_in[5];
  const float* Wi         = (const float*)d_in[6];
  const float* Wh         = (const float*)d_in[7];
  const float* bl         = (const float*)d_in[8];
  const float* Wa         = (const float*)d_in[9];
  const float* ba         = (const float*)d_in[10];
  float* out = (float*)d_out;                       // f32 (r5 probe)
  unsigned short* frg = (unsigned short*)d_ws;      // 409.6 KB of A-fragments

  build_frags_kernel<<<25, 256, 0, stream>>>(Wi, Wh, frg);
  dim3 grid(BTOT / NB);   // 256 blocks -> 1 per CU
  dim3 block(NTHR);
  idm_sim_kernel<<<grid, block, 0, stream>>>(sampled_z, idm_params, idm_s, sdv_acts,
                                             W1, b1, Wi, Wh, bl, Wa, ba, frg, out);
}